// Round 12
// baseline (165.629 us; speedup 1.0000x reference)
//
#include <hip/hip_runtime.h>
#include <math.h>

// ws layout (floats)
#define WS_WEFF 0        // [9 bc][25 t][48 (a*9+ud, pad)] = 10800
#define WS_M    10880    // padded [4][31][32] = 3968
#define WS_OFF  14912    // off0[4], off1[4]
#define WS_FEA  16384    // [260][260][36] = 2,433,600 floats
#define FEA_ROW 9360     // 260*36

// ---------------------------------------------------------------------------
// Prep body (bid 0..15): routing + 4-parity MLP + we/wc/T + clipped composed
// kernels (new [bc][t][48] layout) + padded M.  Logic verified R2..R10.
// ---------------------------------------------------------------------------
__device__ __forceinline__ void prep_body(
    int bid, int tid,
    const float* __restrict__ WE,  const float* __restrict__ WC,
    const float* __restrict__ W2,
    const float* __restrict__ bw1, const float* __restrict__ bb1,
    const float* __restrict__ bw2, const float* __restrict__ bb2,
    const float* __restrict__ r2w, const float* __restrict__ r2b,
    const float* __restrict__ ow,  const float* __restrict__ ob,
    const float* __restrict__ l1w, const float* __restrict__ l1b,
    const float* __restrict__ l2w, const float* __restrict__ l2b,
    float* __restrict__ ws,
    float* weL, float* wcL, float* TL, float* e1L, float* r2cL,
    float* rsumS, float* logitsL)
{
    const int lane = tid & 63, wid = tid >> 6;

    if (wid < 2) {
        float chv = wid ? 0.25f : -0.25f;
        int o = lane;
        float h = fmaxf(0.5f*l1w[2*o] + chv*l1w[2*o+1] + l1b[o], 0.f);
        float a0 = h*l2w[o], a1 = h*l2w[64+o], a2 = h*l2w[128+o], a3 = h*l2w[192+o];
        for (int off = 32; off; off >>= 1) {
            a0 += __shfl_down(a0, off); a1 += __shfl_down(a1, off);
            a2 += __shfl_down(a2, off); a3 += __shfl_down(a3, off);
        }
        if (lane == 0) {
            logitsL[wid*4+0] = a0 + l2b[0]; logitsL[wid*4+1] = a1 + l2b[1];
            logitsL[wid*4+2] = a2 + l2b[2]; logitsL[wid*4+3] = a3 + l2b[3];
        }
    }
    {
        float chv = (wid & 2) ? 0.25f : -0.25f;   // y parity
        float cwv = (wid & 1) ? 0.25f : -0.25f;   // x parity
        int o = lane;
        e1L[wid*64+o] = fmaxf(0.5f*bw1[3*o] + chv*bw1[3*o+1] + cwv*bw1[3*o+2] + bb1[o], 0.f);
    }
    __syncthreads();

    if (tid == 0) {
        float rs0=0.f, rs1=0.f, rs2=0.f, rs3=0.f;
        for (int r = 0; r < 2; ++r) {
            float l0=logitsL[r*4+0], l1v=logitsL[r*4+1], l2v=logitsL[r*4+2], l3=logitsL[r*4+3];
            float mx = fmaxf(fmaxf(l0,l1v), fmaxf(l2v,l3));
            float e0=expf(l0-mx), e1=expf(l1v-mx), e2=expf(l2v-mx), e3=expf(l3-mx);
            float s = e0+e1+e2+e3;
            rs0+=e0/s; rs1+=e1/s; rs2+=e2/s; rs3+=e3/s;
        }
        rsumS[0]=rs0; rsumS[1]=rs1; rsumS[2]=rs2; rsumS[3]=rs3;
    }
    {
        int o = lane;
        float acc = bb2[o];
        #pragma unroll 8
        for (int i = 0; i < 64; ++i) acc += e1L[wid*64+i]*bw2[o*64+i];
        float e2v = fmaxf(acc, 0.f);
        float v0 = e2v*ow[o],       v1 = e2v*ow[64+o];
        float r0 = e2v*r2w[o],      r1 = e2v*r2w[64+o];
        float r2v= e2v*r2w[128+o],  r3 = e2v*r2w[192+o];
        for (int off = 32; off; off >>= 1) {
            v0 += __shfl_down(v0, off);  v1 += __shfl_down(v1, off);
            r0 += __shfl_down(r0, off);  r1 += __shfl_down(r1, off);
            r2v+= __shfl_down(r2v, off); r3 += __shfl_down(r3, off);
        }
        if (lane == 0) {
            if (bid == 0) { ws[WS_OFF + wid] = v0 + ob[0]; ws[WS_OFF + 4 + wid] = v1 + ob[1]; }
            r2cL[wid*4+0] = 1.f/(1.f+expf(-(r0 + r2b[0])));
            r2cL[wid*4+1] = 1.f/(1.f+expf(-(r1 + r2b[1])));
            r2cL[wid*4+2] = 1.f/(1.f+expf(-(r2v+ r2b[2])));
            r2cL[wid*4+3] = 1.f/(1.f+expf(-(r3 + r2b[3])));
        }
    }
    __syncthreads();

    {
        float rs0=rsumS[0], rs1=rsumS[1], rs2=rsumS[2], rs3=rsumS[3];
        for (int idx = tid; idx < 1440; idx += 256) {
            weL[idx] = rs0*WE[idx] + rs1*WE[1440+idx] + rs2*WE[2880+idx] + rs3*WE[4320+idx];
            wcL[idx] = rs0*WC[idx] + rs1*WC[1440+idx] + rs2*WC[2880+idx] + rs3*WC[4320+idx];
        }
    }
    __syncthreads();

    for (int idx = tid; idx < 2025; idx += 256) {
        int s = idx / 45, t = idx % 45;
        float acc = 0.f;
        #pragma unroll 8
        for (int k = 0; k < 32; ++k) acc += wcL[k*45+s] * weL[k*45+t];
        TL[idx] = acc;
    }
    __syncthreads();

    {   // clipped composed kernels -> [bc][t][48] layout
        const int c0 = bid*633, c1 = (c0+633 < 10125) ? c0+633 : 10125;
        for (int idx = c0 + tid; idx < c1; idx += 256) {
            int bc = idx / 1125, r = idx - bc*1125;
            int t  = r / 45,     r2 = r - t*45;
            int a  = r2 / 9,     ud = r2 - a*9;
            int b  = bc / 3,     c  = bc - b*3;
            int uy = t / 5,      ux = t - uy*5;
            int sdlo = (a==0)?2:((a==1)?1:0);
            int sdhi = (a==4)?2:((a==3)?3:4);
            int sylo = (b==0)?1:0, syhi = (b==2)?1:2;
            int sxlo = (c==0)?1:0, sxhi = (c==2)?1:2;
            if (sdlo < ud-4) sdlo = ud-4;
            if (sdhi > ud)   sdhi = ud;
            if (sylo < uy-2) sylo = uy-2;
            if (syhi > uy)   syhi = uy;
            if (sxlo < ux-2) sxlo = ux-2;
            if (sxhi > ux)   sxhi = ux;
            float acc = 0.f;
            for (int sd = sdlo; sd <= sdhi; ++sd)
                for (int sy = sylo; sy <= syhi; ++sy)
                    for (int sx = sxlo; sx <= sxhi; ++sx)
                        acc += TL[(sd*9+sy*3+sx)*45 + (ud-sd)*9 + (uy-sy)*3 + (ux-sx)];
            ws[WS_WEFF + bc*1200 + t*48 + a*9 + ud] = acc;
        }
    }

    {   // padded M: [cls][i][32], j==31 -> 0
        const int c0 = bid*248, c1 = c0+248;
        for (int idx = c0 + tid; idx < c1; idx += 256) {
            int cls = idx / 992, r = idx - cls*992;
            int i = r >> 5, j = r & 31;
            float acc = 0.f;
            if (j < 31) {
                #pragma unroll
                for (int e = 0; e < 4; ++e) acc += r2cL[cls*4+e]*W2[e*961 + i*31 + j];
            }
            ws[WS_M + idx] = acc;
        }
    }
}

// ---------------------------------------------------------------------------
// Fill body: one fea position per thread, d-contiguous float4 stores.
// ---------------------------------------------------------------------------
__device__ __forceinline__ void fill_body(
    int fb, int tid, const float* __restrict__ x,
    const float* __restrict__ bw1, const float* __restrict__ bb1,
    const float* __restrict__ bw2, const float* __restrict__ bb2,
    const float* __restrict__ ow,  const float* __restrict__ ob,
    float* __restrict__ ws, float* e1L, float* offS)
{
    const int lane = tid & 63, wid = tid >> 6;
    {
        float chv = (wid & 2) ? 0.25f : -0.25f;
        float cwv = (wid & 1) ? 0.25f : -0.25f;
        int o = lane;
        e1L[wid*64+o] = fmaxf(0.5f*bw1[3*o] + chv*bw1[3*o+1] + cwv*bw1[3*o+2] + bb1[o], 0.f);
    }
    __syncthreads();
    {
        int o = lane;
        float acc = bb2[o];
        #pragma unroll 8
        for (int i = 0; i < 64; ++i) acc += e1L[wid*64+i]*bw2[o*64+i];
        float e2v = fmaxf(acc, 0.f);
        float v0 = e2v*ow[o], v1 = e2v*ow[64+o];
        for (int off = 32; off; off >>= 1) {
            v0 += __shfl_down(v0, off); v1 += __shfl_down(v1, off);
        }
        if (lane == 0) { offS[wid] = v0 + ob[0]; offS[4+wid] = v1 + ob[1]; }
    }
    __syncthreads();

    const int fpos = fb*256 + tid;
    if (fpos >= 67600) return;
    const int gy2 = fpos / 260, gx2 = fpos - gy2*260;
    const int gy = gy2 - 2, gx = gx2 - 2;
    float* dst = ws + WS_FEA + (size_t)(gy2*260 + gx2)*36;

    if (gy < 0 || gy >= 256 || gx < 0 || gx >= 256) {
        float4 z = make_float4(0.f,0.f,0.f,0.f);
        #pragma unroll
        for (int c4 = 0; c4 < 9; ++c4) *(float4*)(dst + c4*4) = z;
        return;
    }
    const int cls = ((gy & 1) << 1) | (gx & 1);
    float ix = (gx + 0.5f)*0.5f - 0.5f + offS[cls];
    float iy = (gy + 0.5f)*0.5f - 0.5f + offS[4+cls];
    float xf = floorf(ix), yf = floorf(iy);
    float wx = ix - xf, wy = iy - yf;
    int xi = (int)xf, yi = (int)yf;
    const bool vx0 = (xi   >= 0) & (xi   < 128), vx1 = (xi+1 >= 0) & (xi+1 < 128);
    const bool vy0 = (yi   >= 0) & (yi   < 128), vy1 = (yi+1 >= 0) & (yi+1 < 128);
    const float w00 = (1.f-wy)*(1.f-wx) * (float)(vy0 & vx0);
    const float w01 = (1.f-wy)*wx       * (float)(vy0 & vx1);
    const float w10 = wy*(1.f-wx)       * (float)(vy1 & vx0);
    const float w11 = wy*wx             * (float)(vy1 & vx1);
    const int x0i = min(max(xi,   0), 127), x1i = min(max(xi+1, 0), 127);
    const int y0i = min(max(yi,   0), 127), y1i = min(max(yi+1, 0), 127);
    const int i00 = y0i*128 + x0i, i01 = y0i*128 + x1i;
    const int i10 = y1i*128 + x0i, i11 = y1i*128 + x1i;

    #pragma unroll 1
    for (int c4 = 0; c4 < 9; ++c4) {
        float vv[4];
        #pragma unroll
        for (int j = 0; j < 4; ++j) {
            const int c = c4*4 + j;
            float a = 0.f;
            if (c < 31) {
                const float* xc = x + c*16384;
                a = xc[i00]*w00 + xc[i01]*w01 + xc[i10]*w10 + xc[i11]*w11;
            }
            vv[j] = a;
        }
        *(float4*)(dst + c4*4) = make_float4(vv[0], vv[1], vv[2], vv[3]);
    }
}

__global__ __launch_bounds__(256)
void prepfill_kernel(const float* __restrict__ x,
    const float* __restrict__ WE,  const float* __restrict__ WC,
    const float* __restrict__ W2,
    const float* __restrict__ bw1, const float* __restrict__ bb1,
    const float* __restrict__ bw2, const float* __restrict__ bb2,
    const float* __restrict__ r2w, const float* __restrict__ r2b,
    const float* __restrict__ ow,  const float* __restrict__ ob,
    const float* __restrict__ l1w, const float* __restrict__ l1b,
    const float* __restrict__ l2w, const float* __restrict__ l2b,
    float* __restrict__ ws)
{
    __shared__ float weL[1440], wcL[1440], TL[2025], e1L[256];
    __shared__ float r2cL[16], rsumS[4], logitsL[8], offS[8];
    if (blockIdx.x < 16)
        prep_body(blockIdx.x, threadIdx.x, WE,WC,W2,bw1,bb1,bw2,bb2,r2w,r2b,
                  ow,ob,l1w,l1b,l2w,l2b, ws, weL,wcL,TL,e1L,r2cL,rsumS,logitsL);
    else
        fill_body(blockIdx.x-16, threadIdx.x, x, bw1,bb1,bw2,bb2,ow,ob, ws, e1L, offS);
}

// ---------------------------------------------------------------------------
// Conv quarter: SUB owns depths [SUB*8, SUB*8+7] (SUB3: +6).  Cols from
// GLOBAL fea (float4, prefetched 1 tap ahead).  Weights via wg pointer:
// uniform (s_load) at the main call site, per-lane at the edge-redo site.
// ---------------------------------------------------------------------------
template<int SUB>
__device__ __forceinline__ void conv_q(const float* __restrict__ fea,
                                       const float* __restrict__ wg,
                                       int gy, int gx, float* o2, float* fsc)
{
    const int off = (SUB==0) ? 0 : ((SUB==1) ? 4 : ((SUB==2) ? 12 : 20));
    const float* fbase = fea + ((size_t)gy*260 + gx)*36 + off;
    float4 p0 = *(const float4*)(fbase),   p1 = *(const float4*)(fbase+4);
    float4 p2 = *(const float4*)(fbase+8), p3 = *(const float4*)(fbase+12);

    #pragma unroll 1
    for (int t = 0; t < 25; ++t) {
        float4 n0, n1, n2, n3;
        if (t < 24) {
            const int t2 = t+1, uy = t2/5, ux = t2-uy*5;
            const float* fp = fbase + (uy*260 + ux)*36;
            n0 = *(const float4*)(fp);   n1 = *(const float4*)(fp+4);
            n2 = *(const float4*)(fp+8); n3 = *(const float4*)(fp+12);
        }
        float c[20];
        if (SUB == 0) {
            c[0]=0.f; c[1]=0.f; c[2]=0.f; c[3]=0.f;
            c[4]=p0.x; c[5]=p0.y; c[6]=p0.z; c[7]=p0.w;
            c[8]=p1.x; c[9]=p1.y; c[10]=p1.z; c[11]=p1.w;
            c[12]=p2.x; c[13]=p2.y; c[14]=p2.z; c[15]=p2.w;
            c[16]=p3.x; c[17]=p3.y; c[18]=p3.z; c[19]=p3.w;
        } else {
            c[0]=p0.x; c[1]=p0.y; c[2]=p0.z; c[3]=p0.w;
            c[4]=p1.x; c[5]=p1.y; c[6]=p1.z; c[7]=p1.w;
            c[8]=p2.x; c[9]=p2.y; c[10]=p2.z; c[11]=p2.w;
            c[12]=p3.x; c[13]=p3.y; c[14]=p3.z; c[15]=p3.w;
            c[16]=0.f; c[17]=0.f; c[18]=0.f; c[19]=0.f;
        }
        const float* wt = wg + t*48;
        float w2[9];
        #pragma unroll
        for (int u = 0; u < 9; ++u) w2[u] = wt[18+u];
        if (SUB == 0) {
            float w0[9], w1[9];
            #pragma unroll
            for (int u = 0; u < 9; ++u) { w0[u] = wt[u]; w1[u] = wt[9+u]; }
            #pragma unroll
            for (int u = 0; u < 9; ++u) {
                o2[0] += w0[u]*c[u];
                o2[1] += w1[u]*c[1+u];
            }
            #pragma unroll
            for (int j = 2; j < 8; ++j) {
                #pragma unroll
                for (int u = 0; u < 9; ++u) o2[j] += w2[u]*c[j+u];
            }
        } else if (SUB == 3) {
            float w3[9], w4[9];
            #pragma unroll
            for (int u = 0; u < 9; ++u) { w3[u] = wt[27+u]; w4[u] = wt[36+u]; }
            #pragma unroll
            for (int j = 0; j < 5; ++j) {
                #pragma unroll
                for (int u = 0; u < 9; ++u) o2[j] += w2[u]*c[j+u];
            }
            #pragma unroll
            for (int u = 0; u < 9; ++u) {
                o2[5] += w3[u]*c[5+u];
                o2[6] += w4[u]*c[6+u];
            }
        } else {
            #pragma unroll
            for (int j = 0; j < 8; ++j) {
                #pragma unroll
                for (int u = 0; u < 9; ++u) o2[j] += w2[u]*c[j+u];
            }
        }
        if (t == 12) {   // center: conv2 residual (+fea) and fea0 stash
            #pragma unroll
            for (int k = 0; k < 8; ++k) { fsc[k] = c[4+k]; o2[k] += c[4+k]; }
        }
        p0 = n0; p1 = n1; p2 = n2; p3 = n3;
    }
}

// ---------------------------------------------------------------------------
// Conv kernel: 512 blocks (16x8 tile) x 512 threads = 128 px x 4 depth-quarters.
// All blocks co-resident (16 waves/CU).  LDS: MsL (pitch-1000) + o2x only.
// ---------------------------------------------------------------------------
__global__ __launch_bounds__(512, 4)
void conv_kernel(const float* __restrict__ ws, float* __restrict__ out)
{
    __shared__ float MsL[4000];    // [4][31][32] at cls-pitch 1000 (conflict-free)
    __shared__ float o2x[4224];    // [128][33]
    const int tid = threadIdx.x;
    const int x0 = blockIdx.x * 16, y0 = blockIdx.y * 8;

    for (int i4 = tid; i4 < 992; i4 += 512) {
        int cls = i4 / 248, r4 = i4 - cls*248;
        *(float4*)(MsL + cls*1000 + r4*4) = *(const float4*)(ws + WS_M + i4*4);
    }
    __syncthreads();

    const int px = tid & 127, sub = tid >> 7;      // sub uniform per wave
    const int lx = px & 15, ly = px >> 4;
    const int gx = x0 + lx, gy = y0 + ly;
    const int bcls = (gy == 0) ? 0 : ((gy == 255) ? 2 : 1);
    const int ccls = (gx == 0) ? 0 : ((gx == 255) ? 2 : 1);
    const int bc = bcls*3 + ccls;
    const float* fea = ws + WS_FEA;
    const float* wgu = ws + WS_WEFF + 4*1200;      // interior cfg, uniform

    float o2[8], fsc[8];
    #pragma unroll
    for (int k = 0; k < 8; ++k) o2[k] = 0.f;

    if      (sub == 0) conv_q<0>(fea, wgu, gy, gx, o2, fsc);
    else if (sub == 1) conv_q<1>(fea, wgu, gy, gx, o2, fsc);
    else if (sub == 2) conv_q<2>(fea, wgu, gy, gx, o2, fsc);
    else               conv_q<3>(fea, wgu, gy, gx, o2, fsc);

    if (bc != 4) {   // edge lanes: redo with per-lane clipped weights
        #pragma unroll
        for (int k = 0; k < 8; ++k) o2[k] = 0.f;
        const float* wgl = ws + WS_WEFF + bc*1200;
        if      (sub == 0) conv_q<0>(fea, wgl, gy, gx, o2, fsc);
        else if (sub == 1) conv_q<1>(fea, wgl, gy, gx, o2, fsc);
        else if (sub == 2) conv_q<2>(fea, wgl, gy, gx, o2, fsc);
        else               conv_q<3>(fea, wgl, gy, gx, o2, fsc);
    }

    const int i0 = sub*8, ni = (sub == 3) ? 7 : 8;
    #pragma unroll
    for (int k = 0; k < 8; ++k)
        if (k < ni) o2x[px*33 + i0 + k] = o2[k];
    __syncthreads();

    float o2f[32];
    #pragma unroll
    for (int j = 0; j < 31; ++j) o2f[j] = o2x[px*33 + j];
    o2f[31] = 0.f;

    const int cls = ((gy & 1) << 1) | (gx & 1);
    const float* Mb = MsL + cls*1000;
    #pragma unroll 1
    for (int k = 0; k < ni; ++k) {
        const int i = i0 + k;
        float acc = fsc[k];
        #pragma unroll
        for (int q = 0; q < 8; ++q) {
            float4 m = *(const float4*)(Mb + i*32 + q*4);
            acc += m.x*o2f[4*q] + m.y*o2f[4*q+1] + m.z*o2f[4*q+2] + m.w*o2f[4*q+3];
        }
        out[i*65536 + gy*256 + gx] = acc;
    }
}

extern "C" void kernel_launch(void* const* d_in, const int* in_sizes, int n_in,
                              void* d_out, int out_size, void* d_ws, size_t ws_size,
                              hipStream_t stream)
{
    const float* x   = (const float*)d_in[0];
    const float* WE  = (const float*)d_in[2];
    const float* WC  = (const float*)d_in[3];
    const float* W2  = (const float*)d_in[4];
    const float* bw1 = (const float*)d_in[5];
    const float* bb1 = (const float*)d_in[6];
    const float* bw2 = (const float*)d_in[7];
    const float* bb2 = (const float*)d_in[8];
    const float* r2w = (const float*)d_in[9];
    const float* r2b = (const float*)d_in[10];
    const float* ow  = (const float*)d_in[11];
    const float* ob  = (const float*)d_in[12];
    const float* l1w = (const float*)d_in[13];
    const float* l1b = (const float*)d_in[14];
    const float* l2w = (const float*)d_in[15];
    const float* l2b = (const float*)d_in[16];
    float* ws  = (float*)d_ws;
    float* out = (float*)d_out;

    hipLaunchKernelGGL(prepfill_kernel, dim3(281), dim3(256), 0, stream,
                       x, WE, WC, W2, bw1, bb1, bw2, bb2, r2w, r2b,
                       ow, ob, l1w, l1b, l2w, l2b, ws);
    hipLaunchKernelGGL(conv_kernel, dim3(16, 32), dim3(512), 0, stream,
                       ws, out);
}